// Round 4
// baseline (360.029 us; speedup 1.0000x reference)
//
#include <hip/hip_runtime.h>

typedef __bf16 bf16_t;
typedef __attribute__((ext_vector_type(4))) __bf16 bf16x4;
typedef __attribute__((ext_vector_type(8))) __bf16 bf16x8;
typedef __attribute__((ext_vector_type(4))) float floatx4;

#define LN_EPS 1e-5f

// async global->LDS, 16B per lane: LDS dest = wave-uniform base + lane*16
__device__ __forceinline__ void dma16(const void* g, void* l) {
    __builtin_amdgcn_global_load_lds(
        (const __attribute__((address_space(1))) void*)g,
        (__attribute__((address_space(3))) void*)l, 16, 0, 0);
}

// wbf layout (bf16 elements): [Wq 16384][Wk 16384][Wv 16384][Wo 16384][Wib 262144][Wtb 98304]
#define WBF_WI 65536
#define WBF_WT (65536 + 262144)

// =====================================================================
// K0: init c_all with bias; convert Wq/Wk/Wv/Wo/Wi/Wt -> bf16.
// blocks 0..2175: c_all (557056 float4). blocks 2176..2591: weights
// (106496 float4 total, 256/block).
// =====================================================================
__global__ __launch_bounds__(256) void k0_prep(
    const float* __restrict__ bi, const float* __restrict__ bt,
    const float* __restrict__ Wq, const float* __restrict__ Wk,
    const float* __restrict__ Wv, const float* __restrict__ Wo,
    const float* __restrict__ Wi, const float* __restrict__ Wt,
    float* __restrict__ c_all, bf16_t* __restrict__ wbf)
{
    const int b = blockIdx.x;
    if (b < 2176) {
        int i = b * 256 + threadIdx.x;
        int c4 = i & 31;
        float4 a = ((const float4*)bi)[c4];
        float4 bb = ((const float4*)bt)[c4];
        float4 v; v.x = a.x + bb.x; v.y = a.y + bb.y; v.z = a.z + bb.z; v.w = a.w + bb.w;
        ((float4*)c_all)[i] = v;
    } else {
        int i4 = (b - 2176) * 256 + threadIdx.x;     // 0..106495
        const float* src; int dst;
        if (i4 < 16384) {
            int which = i4 >> 12, off4 = i4 & 4095;
            src = ((which == 0) ? Wq : (which == 1) ? Wk : (which == 2) ? Wv : Wo) + off4 * 4;
            dst = which * 16384 + off4 * 4;
        } else if (i4 < 16384 + 65536) {
            int off4 = i4 - 16384;
            src = Wi + off4 * 4; dst = WBF_WI + off4 * 4;
        } else {
            int off4 = i4 - (16384 + 65536);
            src = Wt + off4 * 4; dst = WBF_WT + off4 * 4;
        }
        float4 v = *(const float4*)src;
        bf16x4 pk; pk.x = (bf16_t)v.x; pk.y = (bf16_t)v.y;
                   pk.z = (bf16_t)v.z; pk.w = (bf16_t)v.w;
        *(bf16x4*)&wbf[dst] = pk;
    }
}

// =====================================================================
// K1: c_all += [img|txt] @ [Wi|Wt]^T   (split-K x4, atomic epilogue).
// BARRIER-FREE: no LDS, no __syncthreads in the K-loop. Each wave owns a
// 32x64 output tile (2x4 mfma 16x16x32). Per 32-K slab per lane:
//   A: 2 x (2 float4 fp32 loads, 16 rows x 128B contiguous per instr)
//   B: 4 x bf16x8 (16B) from pre-converted bf16 weights (L2-resident).
// 8 loads : 8 MFMA, unroll x2 -> compiler software-pipelines with
// vmcnt(N), never a full drain (the R3 barrier-drain was the stall).
// =====================================================================
#define K1_MFMA8(FA0, FA1)                                                     \
    acc[0][0] = __builtin_amdgcn_mfma_f32_16x16x32_bf16(FA0, fb0, acc[0][0], 0, 0, 0); \
    acc[0][1] = __builtin_amdgcn_mfma_f32_16x16x32_bf16(FA0, fb1, acc[0][1], 0, 0, 0); \
    acc[0][2] = __builtin_amdgcn_mfma_f32_16x16x32_bf16(FA0, fb2, acc[0][2], 0, 0, 0); \
    acc[0][3] = __builtin_amdgcn_mfma_f32_16x16x32_bf16(FA0, fb3, acc[0][3], 0, 0, 0); \
    acc[1][0] = __builtin_amdgcn_mfma_f32_16x16x32_bf16(FA1, fb0, acc[1][0], 0, 0, 0); \
    acc[1][1] = __builtin_amdgcn_mfma_f32_16x16x32_bf16(FA1, fb1, acc[1][1], 0, 0, 0); \
    acc[1][2] = __builtin_amdgcn_mfma_f32_16x16x32_bf16(FA1, fb2, acc[1][2], 0, 0, 0); \
    acc[1][3] = __builtin_amdgcn_mfma_f32_16x16x32_bf16(FA1, fb3, acc[1][3], 0, 0, 0);

#define K1_BODY(A0, A1, B0, B1, B2, B3, K)                                     \
    {                                                                          \
        float4 p00 = *(const float4*)((A0) + (K));                             \
        float4 p01 = *(const float4*)((A0) + (K) + 4);                         \
        float4 p10 = *(const float4*)((A1) + (K));                             \
        float4 p11 = *(const float4*)((A1) + (K) + 4);                         \
        bf16x8 fb0 = *(const bf16x8*)((B0) + (K));                             \
        bf16x8 fb1 = *(const bf16x8*)((B1) + (K));                             \
        bf16x8 fb2 = *(const bf16x8*)((B2) + (K));                             \
        bf16x8 fb3 = *(const bf16x8*)((B3) + (K));                             \
        bf16x8 fa0, fa1;                                                       \
        fa0[0] = (bf16_t)p00.x; fa0[1] = (bf16_t)p00.y;                        \
        fa0[2] = (bf16_t)p00.z; fa0[3] = (bf16_t)p00.w;                        \
        fa0[4] = (bf16_t)p01.x; fa0[5] = (bf16_t)p01.y;                        \
        fa0[6] = (bf16_t)p01.z; fa0[7] = (bf16_t)p01.w;                        \
        fa1[0] = (bf16_t)p10.x; fa1[1] = (bf16_t)p10.y;                        \
        fa1[2] = (bf16_t)p10.z; fa1[3] = (bf16_t)p10.w;                        \
        fa1[4] = (bf16_t)p11.x; fa1[5] = (bf16_t)p11.y;                        \
        fa1[6] = (bf16_t)p11.z; fa1[7] = (bf16_t)p11.w;                        \
        K1_MFMA8(fa0, fa1)                                                     \
    }

__global__ __launch_bounds__(256, 4) void k1_gemm(
    const float* __restrict__ qimg, const float* __restrict__ qtxt,
    const float* __restrict__ simg, const float* __restrict__ stxt,
    const bf16_t* __restrict__ wbf, float* __restrict__ c_all)
{
    const bf16_t* Wib = wbf + WBF_WI;
    const bf16_t* Wtb = wbf + WBF_WT;

    const int tid  = threadIdx.x;
    const int m0   = blockIdx.x * 64;
    const int chnk = blockIdx.y;
    const bool isq = (m0 < 16384);
    const int rb   = isq ? m0 : (m0 - 16384);
    const float* Aimg = isq ? qimg : simg;
    const float* Atxt = isq ? qtxt : stxt;

    const int wid  = tid >> 6;
    const int lane = tid & 63;
    const int quad = lane >> 4;
    const int l16  = lane & 15;
    const int wr   = wid >> 1;
    const int wc   = wid & 1;

    const int ar0 = rb + wr * 32 + l16;      // A row, mt=0 (mt=1 is +16)
    const int bc0 = wc * 64 + l16;           // B row (output col), nt=0

    floatx4 acc[2][4];
#pragma unroll
    for (int i = 0; i < 2; ++i)
#pragma unroll
        for (int j = 0; j < 4; ++j) acc[i][j] = (floatx4)0.f;

    const int kb = chnk * 704;
    const int ke = kb + 704;

    // --- img segment (stride 2048) ---
    const int ie = (ke < 2048) ? ke : 2048;
    if (kb < ie) {
        const float*  a0 = Aimg + (size_t)ar0 * 2048 + quad * 8 + kb;
        const float*  a1 = a0 + (size_t)16 * 2048;
        const bf16_t* b0 = Wib + (size_t)bc0 * 2048 + quad * 8 + kb;
        const bf16_t* b1 = b0 + (size_t)16 * 2048;
        const bf16_t* b2 = b0 + (size_t)32 * 2048;
        const bf16_t* b3 = b0 + (size_t)48 * 2048;
        const int n = ie - kb;
#pragma unroll 2
        for (int k = 0; k < n; k += 32) K1_BODY(a0, a1, b0, b1, b2, b3, k)
    }
    // --- txt segment (stride 768) ---
    const int ts = (kb > 2048) ? kb : 2048;
    if (ts < ke) {
        const int off = ts - 2048;
        const float*  a0 = Atxt + (size_t)ar0 * 768 + quad * 8 + off;
        const float*  a1 = a0 + (size_t)16 * 768;
        const bf16_t* b0 = Wtb + (size_t)bc0 * 768 + quad * 8 + off;
        const bf16_t* b1 = b0 + (size_t)16 * 768;
        const bf16_t* b2 = b0 + (size_t)32 * 768;
        const bf16_t* b3 = b0 + (size_t)48 * 768;
        const int n = ke - ts;
#pragma unroll 2
        for (int k = 0; k < n; k += 32) K1_BODY(a0, a1, b0, b1, b2, b3, k)
    }

    // epilogue: atomic accumulate (bias pre-set by k0)
#pragma unroll
    for (int nt = 0; nt < 4; ++nt) {
        int col = wc * 64 + nt * 16 + l16;
#pragma unroll
        for (int mt = 0; mt < 2; ++mt)
#pragma unroll
            for (int r = 0; r < 4; ++r) {
                int row = wr * 32 + mt * 16 + quad * 4 + r;
                unsafeAtomicAdd(&c_all[(size_t)(m0 + row) * 128 + col], acc[mt][nt][r]);
            }
    }
}

// =====================================================================
// K2: fully fused tail. 1 block = 1 task. Computes the task's 4 support
// prototypes (k3's work) in-block, then the 64-query tail + logits.
// Wv/Wo staged once and shared by support matvecs + query MFMAs.
// =====================================================================
#define K2_ST 136

__global__ __launch_bounds__(256) void k2_fused(
    const float* __restrict__ c_all, const bf16_t* __restrict__ wbf,
    const float* __restrict__ bq, const float* __restrict__ bk,
    const float* __restrict__ bv, const float* __restrict__ bo,
    const float* __restrict__ g1, const float* __restrict__ b1,
    const float* __restrict__ g2, const float* __restrict__ b2,
    float* __restrict__ out)
{
    __shared__ bf16_t tT[64 * K2_ST];     // query token tile (17.4 KB)
    __shared__ bf16_t tW[128 * 128];      // weight buffer, DMA target (32 KB)
    __shared__ float  cs[4][128];         // support LN buffer
    __shared__ float  qkv[3][4][128];     // support q/k/v (q,k slots reused later)
    __shared__ float  att[4][4];
    __shared__ float  pl[4][132];         // prototypes

    const int tid  = threadIdx.x;
    const int wid  = tid >> 6;
    const int lane = tid & 63;
    const int quad = lane >> 4;
    const int l16  = lane & 15;
    const int task = blockIdx.x;
    const int t0   = task * 64;
    const int r0   = wid * 16;
    const int jr4  = lane >> 4;
    const int jp   = lane & 15;

    // ---- stage Wq (DMA) ----
#pragma unroll
    for (int ii = 0; ii < 8; ++ii) {
        int i = 8 * wid + ii;
        int row = 4 * i + jr4;
        int c = jp ^ (row & 15);
        dma16(wbf + 0 * 16384 + row * 128 + c * 8, (char*)tW + i * 1024);
    }

    // per-lane epilogue constants
    float bvr[8], g2r[8], b2r[8], bor[8];
#pragma unroll
    for (int nt = 0; nt < 8; ++nt) {
        int col = nt * 16 + l16;
        bvr[nt] = bv[col]; g2r[nt] = g2[col]; b2r[nt] = b2[col]; bor[nt] = bo[col];
    }

    // ---- query LN1 -> tT (8 rows/wave in parallel, 2 passes) ----
    {
        const int g8 = lane >> 3, s8 = lane & 7;
        float g1a[16], b1a[16];
#pragma unroll
        for (int mm = 0; mm < 4; ++mm) {
            *(float4*)&g1a[mm * 4] = ((const float4*)(g1 + s8 * 16))[mm];
            *(float4*)&b1a[mm * 4] = ((const float4*)(b1 + s8 * 16))[mm];
        }
#pragma unroll
        for (int p = 0; p < 2; ++p) {
            int rloc = r0 + p * 8 + g8;
            const float* src = c_all + (size_t)(t0 + rloc) * 128 + s8 * 16;
            float v[16];
#pragma unroll
            for (int mm = 0; mm < 4; ++mm) *(float4*)&v[mm * 4] = ((const float4*)src)[mm];
            float s = 0.f, q = 0.f;
#pragma unroll
            for (int m = 0; m < 16; ++m) { s += v[m]; q += v[m] * v[m]; }
#pragma unroll
            for (int m = 1; m < 8; m <<= 1) { s += __shfl_xor(s, m); q += __shfl_xor(q, m); }
            float mean = s * (1.f / 128.f);
            float var  = q * (1.f / 128.f) - mean * mean;
            float rs   = rsqrtf(var + LN_EPS);
            bf16x8 o0, o1;
#pragma unroll
            for (int m = 0; m < 8; ++m) o0[m] = (bf16_t)((v[m] - mean) * rs * g1a[m] + b1a[m]);
#pragma unroll
            for (int m = 0; m < 8; ++m) o1[m] = (bf16_t)((v[8 + m] - mean) * rs * g1a[8 + m] + b1a[8 + m]);
            *(bf16x8*)&tT[rloc * K2_ST + s8 * 16]     = o0;
            *(bf16x8*)&tT[rloc * K2_ST + s8 * 16 + 8] = o1;
        }
    }
    // ---- support LN1 -> cs (wave per token row) ----
    {
        const float* src = c_all + (size_t)(16384 + task * 4 + wid) * 128;
        float x0 = src[lane], x1 = src[64 + lane];
        float s = x0 + x1, q = x0 * x0 + x1 * x1;
#pragma unroll
        for (int m = 1; m < 64; m <<= 1) { s += __shfl_xor(s, m); q += __shfl_xor(q, m); }
        float mean = s * (1.f / 128.f);
        float var  = q * (1.f / 128.f) - mean * mean;
        float rs   = rsqrtf(var + LN_EPS);
        cs[wid][lane]      = (x0 - mean) * rs * g1[lane] + b1[lane];
        cs[wid][64 + lane] = (x1 - mean) * rs * g1[64 + lane] + b1[64 + lane];
    }
    __syncthreads();   // B1: Wq drained, tT/cs visible

    // ---- support q = cs @ Wq^T + bq -> qkv[0] ----
#pragma unroll
    for (int j = 0; j < 2; ++j) {
        int o = tid + j * 256, s = o >> 7, n = o & 127;
        const float4* c4 = (const float4*)cs[s];
        float acc = 0.f;
#pragma unroll
        for (int c = 0; c < 16; ++c) {
            bf16x8 wv = *(const bf16x8*)&tW[n * 128 + ((c ^ (n & 15)) << 3)];
            float4 a0 = c4[c * 2], a1 = c4[c * 2 + 1];
            acc += a0.x * (float)wv[0] + a0.y * (float)wv[1]
                 + a0.z * (float)wv[2] + a0.w * (float)wv[3]
                 + a1.x * (float)wv[4] + a1.y * (float)wv[5]
                 + a1.z * (float)wv[6] + a1.w * (float)wv[7];
        }
        qkv[0][s][n] = acc + bq[n];
    }
    __syncthreads();   // B2: done reading Wq
#pragma unroll
    for (int ii = 0; ii < 8; ++ii) {   // stage Wk
        int i = 8 * wid + ii;
        int row = 4 * i + jr4;
        int c = jp ^ (row & 15);
        dma16(wbf + 1 * 16384 + row * 128 + c * 8, (char*)tW + i * 1024);
    }
    __syncthreads();   // B3: Wk drained
#pragma unroll
    for (int j = 0; j < 2; ++j) {      // support k -> qkv[1]
        int o = tid + j * 256, s = o >> 7, n = o & 127;
        const float4* c4 = (const float4*)cs[s];
        float acc = 0.f;
#pragma unroll
        for (int c = 0; c < 16; ++c) {
            bf16x8 wv = *(const bf16x8*)&tW[n * 128 + ((c ^ (n & 15)) << 3)];
            float4 a0 = c4[c * 2], a1 = c4[c * 2 + 1];
            acc += a0.x * (float)wv[0] + a0.y * (float)wv[1]
                 + a0.z * (float)wv[2] + a0.w * (float)wv[3]
                 + a1.x * (float)wv[4] + a1.y * (float)wv[5]
                 + a1.z * (float)wv[6] + a1.w * (float)wv[7];
        }
        qkv[1][s][n] = acc + bk[n];
    }
    __syncthreads();   // B4: done reading Wk
#pragma unroll
    for (int ii = 0; ii < 8; ++ii) {   // stage Wv
        int i = 8 * wid + ii;
        int row = 4 * i + jr4;
        int c = jp ^ (row & 15);
        dma16(wbf + 2 * 16384 + row * 128 + c * 8, (char*)tW + i * 1024);
    }
    __syncthreads();   // B5: Wv drained

    // ---- query MFMA1: v = LN1 @ Wv^T + bv ----
    floatx4 acc[8];
#pragma unroll
    for (int nt = 0; nt < 8; ++nt) acc[nt] = (floatx4)0.f;
#pragma unroll
    for (int ks = 0; ks < 4; ++ks) {
        bf16x8 a = *(const bf16x8*)&tT[(r0 + l16) * K2_ST + ks * 32 + quad * 8];
#pragma unroll
        for (int nt = 0; nt < 8; ++nt) {
            bf16x8 b = *(const bf16x8*)&tW[(nt * 16 + l16) * 128 + (((ks * 4 + quad) ^ l16) << 3)];
            acc[nt] = __builtin_amdgcn_mfma_f32_16x16x32_bf16(a, b, acc[nt], 0, 0, 0);
        }
    }
#pragma unroll
    for (int nt = 0; nt < 8; ++nt)
#pragma unroll
        for (int r = 0; r < 4; ++r) acc[nt][r] += bvr[nt];

    // ---- support v -> qkv[2] ----
#pragma unroll
    for (int j = 0; j < 2; ++j) {
        int o = tid + j * 256, s = o >> 7, n = o & 127;
        const float4* c4 = (const float4*)cs[s];
        float a = 0.f;
#pragma unroll
        for (int c = 0; c < 16; ++c) {
            bf16x8 wv = *(const bf16x8*)&tW[n * 128 + ((c ^ (n & 15)) << 3)];
            float4 a0 = c4[c * 2], a1 = c4[c * 2 + 1];
            a += a0.x * (float)wv[0] + a0.y * (float)wv[1]
               + a0.z * (float)wv[2] + a0.w * (float)wv[3]
               + a1.x * (float)wv[4] + a1.y * (float)wv[5]
               + a1.z * (float)wv[6] + a1.w * (float)wv[7];
        }
        qkv[2][s][n] = a + bv[n];
    }
    // ---- attention scores (tid<16) ----
    if (tid < 16) {
        int i = tid >> 2, j = tid & 3;
        const float4* qv = (const float4*)qkv[0][i];
        const float4* kv = (const float4*)qkv[1][j];
        float a = 0.f;
#pragma unroll
        for (int k = 0; k < 32; ++k) {
            float4 x = qv[k], y = kv[k];
            a += x.x * y.x + x.y * y.y + x.z * y.z + x.w * y.w;
        }
        att[i][j] = a * (float)(1.0 / (11.313708498984761 + 1e-8));
    }
    // ---- query LN2 in-register -> tT ----
#pragma unroll
    for (int r = 0; r < 4; ++r) {
        float s = 0.f, q = 0.f;
#pragma unroll
        for (int nt = 0; nt < 8; ++nt) { float x = acc[nt][r]; s += x; q += x * x; }
#pragma unroll
        for (int m = 1; m < 16; m <<= 1) { s += __shfl_xor(s, m); q += __shfl_xor(q, m); }
        float mean = s * (1.f / 128.f);
        float var  = q * (1.f / 128.f) - mean * mean;
        float rs   = rsqrtf(var + LN_EPS);
        int row = r0 + quad * 4 + r;
#pragma unroll
        for (int nt = 0; nt < 8; ++nt)
            tT[row * K2_ST + nt * 16 + l16] = (bf16_t)((acc[nt][r] - mean) * rs * g2r[nt] + b2r[nt]);
    }
    __syncthreads();   // B6: tW(Wv) free, att written
#pragma unroll
    for (int ii = 0; ii < 8; ++ii) {   // stage Wo
        int i = 8 * wid + ii;
        int row = 4 * i + jr4;
        int c = jp ^ (row & 15);
        dma16(wbf + 3 * 16384 + row * 128 + c * 8, (char*)tW + i * 1024);
    }
    if (tid < 4) {  // exact softmax -> +1e-10 -> renorm -> clip
        float s0 = att[tid][0], s1 = att[tid][1], s2 = att[tid][2], s3 = att[tid][3];
        float m = fmaxf(fmaxf(s0, s1), fmaxf(s2, s3));
        float e0 = expf(s0 - m), e1 = expf(s1 - m), e2 = expf(s2 - m), e3 = expf(s3 - m);
        float se = e0 + e1 + e2 + e3;
        float a0 = e0 / se + 1e-10f, a1 = e1 / se + 1e-10f;
        float a2 = e2 / se + 1e-10f, a3 = e3 / se + 1e-10f;
        float t = a0 + a1 + a2 + a3;
        att[tid][0] = fminf(fmaxf(a0 / t, 1e-7f), 1.f);
        att[tid][1] = fminf(fmaxf(a1 / t, 1e-7f), 1.f);
        att[tid][2] = fminf(fmaxf(a2 / t, 1e-7f), 1.f);
        att[tid][3] = fminf(fmaxf(a3 / t, 1e-7f), 1.f);
    }
    __syncthreads();   // B7: Wo drained, softmax done

    // ---- ctx = a @ v -> qkv[0] (reuse) ----
#pragma unroll
    for (int j = 0; j < 2; ++j) {
        int o = tid + j * 256, s = o >> 7, n = o & 127;
        qkv[0][s][n] = att[s][0] * qkv[2][0][n] + att[s][1] * qkv[2][1][n]
                     + att[s][2] * qkv[2][2][n] + att[s][3] * qkv[2][3][n];
    }
    __syncthreads();   // B8
    { // support LN2 -> cs
        float x0 = qkv[0][wid][lane], x1 = qkv[0][wid][64 + lane];
        float s = x0 + x1, q = x0 * x0 + x1 * x1;
#pragma unroll
        for (int m = 1; m < 64; m <<= 1) { s += __shfl_xor(s, m); q += __shfl_xor(q, m); }
        float mean = s * (1.f / 128.f);
        float var  = q * (1.f / 128.f) - mean * mean;
        float rs   = rsqrtf(var + LN_EPS);
        cs[wid][lane]      = (x0 - mean) * rs * g2[lane] + b2[lane];
        cs[wid][64 + lane] = (x1 - mean) * rs * g2[64 + lane] + b2[64 + lane];
    }
    __syncthreads();   // B9

    // ---- support out = LN2 @ Wo^T + bo -> qkv[1] (reuse) ----
#pragma unroll
    for (int j = 0; j < 2; ++j) {
        int o = tid + j * 256, s = o >> 7, n = o & 127;
        const float4* c4 = (const float4*)cs[s];
        float a = 0.f;
#pragma unroll
        for (int c = 0; c < 16; ++c) {
            bf16x8 wv = *(const bf16x8*)&tW[n * 128 + ((c ^ (n & 15)) << 3)];
            float4 a0 = c4[c * 2], a1 = c4[c * 2 + 1];
            a += a0.x * (float)wv[0] + a0.y * (float)wv[1]
               + a0.z * (float)wv[2] + a0.w * (float)wv[3]
               + a1.x * (float)wv[4] + a1.y * (float)wv[5]
               + a1.z * (float)wv[6] + a1.w * (float)wv[7];
        }
        qkv[1][s][n] = a + bo[n];
    }

    // ---- query MFMA2: qf = LN2 @ Wo^T ----
    floatx4 acc2[8];
#pragma unroll
    for (int nt = 0; nt < 8; ++nt) acc2[nt] = (floatx4)0.f;
#pragma unroll
    for (int ks = 0; ks < 4; ++ks) {
        bf16x8 a = *(const bf16x8*)&tT[(r0 + l16) * K2_ST + ks * 32 + quad * 8];
#pragma unroll
        for (int nt = 0; nt < 8; ++nt) {
            bf16x8 b = *(const bf16x8*)&tW[(nt * 16 + l16) * 128 + (((ks * 4 + quad) ^ l16) << 3)];
            acc2[nt] = __builtin_amdgcn_mfma_f32_16x16x32_bf16(a, b, acc2[nt], 0, 0, 0);
        }
    }
    __syncthreads();   // B10: qkv[1] (support out) visible
    { // support normalize -> pl
        float x0 = qkv[1][wid][lane], x1 = qkv[1][wid][64 + lane];
        float q = x0 * x0 + x1 * x1;
#pragma unroll
        for (int m = 1; m < 64; m <<= 1) q += __shfl_xor(q, m);
        float inv = 1.f / fmaxf(sqrtf(q), 1e-8f);
        pl[wid][lane]      = x0 * inv;
        pl[wid][64 + lane] = x1 * inv;
    }
    __syncthreads();   // B11: pl ready

    // ---- query normalize + logits ----
#pragma unroll
    for (int r = 0; r < 4; ++r) {
        float st[8]; float q = 0.f;
#pragma unroll
        for (int nt = 0; nt < 8; ++nt) {
            float x = acc2[nt][r] + bor[nt]; st[nt] = x; q += x * x;
        }
#pragma unroll
        for (int m = 1; m < 16; m <<= 1) q += __shfl_xor(q, m);
        float inv = 1.f / fmaxf(sqrtf(q), 1e-8f);
        float d0 = 0.f, d1 = 0.f, d2 = 0.f, d3 = 0.f;
#pragma unroll
        for (int nt = 0; nt < 8; ++nt) {
            float xn = st[nt] * inv;
            int col = nt * 16 + l16;
            d0 += xn * pl[0][col]; d1 += xn * pl[1][col];
            d2 += xn * pl[2][col]; d3 += xn * pl[3][col];
        }
#pragma unroll
        for (int m = 1; m < 16; m <<= 1) {
            d0 += __shfl_xor(d0, m); d1 += __shfl_xor(d1, m);
            d2 += __shfl_xor(d2, m); d3 += __shfl_xor(d3, m);
        }
        if (l16 == 0) {
            int qi = r0 + quad * 4 + r;
            float* o = out + (size_t)task * 256 + qi * 4;
            o[0] = d0 * 10.f; o[1] = d1 * 10.f; o[2] = d2 * 10.f; o[3] = d3 * 10.f;
        }
    }
}

// =====================================================================
extern "C" void kernel_launch(void* const* d_in, const int* in_sizes, int n_in,
                              void* d_out, int out_size, void* d_ws, size_t ws_size,
                              hipStream_t stream)
{
    const float* simg = (const float*)d_in[0];
    const float* stxt = (const float*)d_in[1];
    const float* qimg = (const float*)d_in[3];
    const float* qtxt = (const float*)d_in[4];
    const float* Wi = (const float*)d_in[5];
    const float* bi = (const float*)d_in[6];
    const float* Wt = (const float*)d_in[7];
    const float* bt = (const float*)d_in[8];
    const float* g1 = (const float*)d_in[9];
    const float* b1 = (const float*)d_in[10];
    const float* Wq = (const float*)d_in[11];
    const float* bq = (const float*)d_in[12];
    const float* Wk = (const float*)d_in[13];
    const float* bk = (const float*)d_in[14];
    const float* Wv = (const float*)d_in[15];
    const float* bv = (const float*)d_in[16];
    const float* g2 = (const float*)d_in[17];
    const float* b2 = (const float*)d_in[18];
    const float* Wo = (const float*)d_in[19];
    const float* bo = (const float*)d_in[20];
    float* out = (float*)d_out;

    float*  c_all = (float*)d_ws;                          // 17408 x 128 f32
    bf16_t* wbf   = (bf16_t*)(c_all + (size_t)17408 * 128); // 425984 bf16

    k0_prep<<<2592, 256, 0, stream>>>(bi, bt, Wq, Wk, Wv, Wo, Wi, Wt, c_all, wbf);
    k1_gemm<<<dim3(272, 4), 256, 0, stream>>>(qimg, qtxt, simg, stxt, wbf, c_all);
    k2_fused<<<256, 256, 0, stream>>>(c_all, wbf, bq, bk, bv, bo, g1, b1, g2, b2, out);
}

// Round 5
// 311.820 us; speedup vs baseline: 1.1546x; 1.1546x over previous
//
#include <hip/hip_runtime.h>

typedef __bf16 bf16_t;
typedef __attribute__((ext_vector_type(4))) __bf16 bf16x4;
typedef __attribute__((ext_vector_type(8))) __bf16 bf16x8;
typedef __attribute__((ext_vector_type(4))) float floatx4;

#define LN_EPS 1e-5f

// async global->LDS, 16B per lane: LDS dest = wave-uniform base + lane*16
__device__ __forceinline__ void dma16(const void* g, void* l) {
    __builtin_amdgcn_global_load_lds(
        (const __attribute__((address_space(1))) void*)g,
        (__attribute__((address_space(3))) void*)l, 16, 0, 0);
}

// wbf layout (bf16): [Wq 16384][Wk 16384][Wv 16384][Wo 16384][Wib 262144][Wtb 98304]
#define WBF_WI 65536
#define WBF_WT (65536 + 262144)

// =====================================================================
// K0: init c_all with bias; convert Wq/Wk/Wv/Wo/Wi/Wt -> bf16.
// =====================================================================
__global__ __launch_bounds__(256) void k0_prep(
    const float* __restrict__ bi, const float* __restrict__ bt,
    const float* __restrict__ Wq, const float* __restrict__ Wk,
    const float* __restrict__ Wv, const float* __restrict__ Wo,
    const float* __restrict__ Wi, const float* __restrict__ Wt,
    float* __restrict__ c_all, bf16_t* __restrict__ wbf)
{
    const int b = blockIdx.x;
    if (b < 2176) {
        int i = b * 256 + threadIdx.x;
        int c4 = i & 31;
        float4 a = ((const float4*)bi)[c4];
        float4 bb = ((const float4*)bt)[c4];
        float4 v; v.x = a.x + bb.x; v.y = a.y + bb.y; v.z = a.z + bb.z; v.w = a.w + bb.w;
        ((float4*)c_all)[i] = v;
    } else {
        int i4 = (b - 2176) * 256 + threadIdx.x;     // 0..106495
        const float* src; int dst;
        if (i4 < 16384) {
            int which = i4 >> 12, off4 = i4 & 4095;
            src = ((which == 0) ? Wq : (which == 1) ? Wk : (which == 2) ? Wv : Wo) + off4 * 4;
            dst = which * 16384 + off4 * 4;
        } else if (i4 < 16384 + 65536) {
            int off4 = i4 - 16384;
            src = Wi + off4 * 4; dst = WBF_WI + off4 * 4;
        } else {
            int off4 = i4 - (16384 + 65536);
            src = Wt + off4 * 4; dst = WBF_WT + off4 * 4;
        }
        float4 v = *(const float4*)src;
        bf16x4 pk; pk.x = (bf16_t)v.x; pk.y = (bf16_t)v.y;
                   pk.z = (bf16_t)v.z; pk.w = (bf16_t)v.w;
        *(bf16x4*)&wbf[dst] = pk;
    }
}

// =====================================================================
// K1: c_all += [img|txt] @ [Wi|Wt]^T   (split-K x4, atomic epilogue).
// BM=64 BN=128 BK=64. Coalesced staging (A: 16 lanes cover one row's
// 256B; B: 8 lanes per 128B row) + register prefetch: next slab's loads
// are issued after the LDS-visible barrier and stay in flight through
// the compute phase (drain happens at the NEXT iteration's barrier).
// LDS 27KB, 4 blocks/CU.
// =====================================================================
#define K1_LD 72   // bf16 stride (64 + 8 pad)

#define K1_LOAD(K0)                                                            \
    {                                                                          \
        const int k0_ = (K0);                                                  \
        const float* ab_; const bf16_t* bb_; int lda_, ldb_;                   \
        if (k0_ < 2048) {                                                      \
            ab_ = Aimg + (size_t)rb * 2048 + k0_; lda_ = 2048;                 \
            bb_ = Wib + k0_; ldb_ = 2048;                                      \
        } else {                                                               \
            ab_ = Atxt + (size_t)rb * 768 + (k0_ - 2048); lda_ = 768;          \
            bb_ = Wtb + (k0_ - 2048); ldb_ = 768;                              \
        }                                                                      \
        _Pragma("unroll")                                                      \
        for (int p = 0; p < 4; ++p)                                            \
            aR[p] = *(const float4*)(ab_ + (size_t)(16 * p + arow) * lda_ + acol); \
        _Pragma("unroll")                                                      \
        for (int p = 0; p < 4; ++p)                                            \
            bR[p] = *(const bf16x8*)(bb_ + (size_t)(32 * p + brow) * ldb_ + bcol); \
    }

__global__ __launch_bounds__(256, 4) void k1_gemm(
    const float* __restrict__ qimg, const float* __restrict__ qtxt,
    const float* __restrict__ simg, const float* __restrict__ stxt,
    const bf16_t* __restrict__ wbf, float* __restrict__ c_all)
{
    __shared__ bf16_t lA[64 * K1_LD];     //  9.2 KB
    __shared__ bf16_t lB[128 * K1_LD];    // 18.4 KB

    const bf16_t* Wib = wbf + WBF_WI;
    const bf16_t* Wtb = wbf + WBF_WT;

    const int tid  = threadIdx.x;
    const int m0   = blockIdx.x * 64;
    const int chnk = blockIdx.y;
    const bool isq = (m0 < 16384);
    const int rb   = isq ? m0 : (m0 - 16384);
    const float* Aimg = isq ? qimg : simg;
    const float* Atxt = isq ? qtxt : stxt;

    const int wid  = tid >> 6;
    const int lane = tid & 63;
    const int quad = lane >> 4;
    const int l16  = lane & 15;
    const int wr   = wid >> 1;
    const int wc   = wid & 1;

    // staging maps: A row = 16p + arow (16 lanes x 16B = full 256B row);
    //               B row = 32p + brow (8 lanes x 16B = full 128B row)
    const int arow = tid >> 4;          // 0..15
    const int acol = (tid & 15) << 2;   // fp32 col
    const int brow = tid >> 3;          // 0..31
    const int bcol = (tid & 7) << 3;    // bf16 col

    float4 aR[4];
    bf16x8 bR[4];

    floatx4 acc[2][4];
#pragma unroll
    for (int i = 0; i < 2; ++i)
#pragma unroll
        for (int j = 0; j < 4; ++j) acc[i][j] = (floatx4)0.f;

    const int kb = chnk * 704;          // 11 slabs of 64; never straddles 2048

    K1_LOAD(kb)
    for (int s = 0; s < 11; ++s) {
        __syncthreads();                // prev compute done reading LDS
#pragma unroll
        for (int p = 0; p < 4; ++p) {   // store A (cvt fp32->bf16)
            bf16x4 pk; pk.x = (bf16_t)aR[p].x; pk.y = (bf16_t)aR[p].y;
                       pk.z = (bf16_t)aR[p].z; pk.w = (bf16_t)aR[p].w;
            *(bf16x4*)&lA[(16 * p + arow) * K1_LD + acol] = pk;
        }
#pragma unroll
        for (int p = 0; p < 4; ++p)     // store B
            *(bf16x8*)&lB[(32 * p + brow) * K1_LD + bcol] = bR[p];
        __syncthreads();                // LDS visible
        if (s + 1 < 11) K1_LOAD(kb + (s + 1) * 64)   // prefetch: in flight during compute

#pragma unroll
        for (int ks = 0; ks < 2; ++ks) {
            bf16x8 af[2], bf[4];
#pragma unroll
            for (int mt = 0; mt < 2; ++mt)
                af[mt] = *(const bf16x8*)&lA[(wr * 32 + mt * 16 + l16) * K1_LD + ks * 32 + quad * 8];
#pragma unroll
            for (int nt = 0; nt < 4; ++nt)
                bf[nt] = *(const bf16x8*)&lB[(wc * 64 + nt * 16 + l16) * K1_LD + ks * 32 + quad * 8];
#pragma unroll
            for (int mt = 0; mt < 2; ++mt)
#pragma unroll
                for (int nt = 0; nt < 4; ++nt)
                    acc[mt][nt] = __builtin_amdgcn_mfma_f32_16x16x32_bf16(
                        af[mt], bf[nt], acc[mt][nt], 0, 0, 0);
        }
    }

#pragma unroll
    for (int nt = 0; nt < 4; ++nt) {
        int col = wc * 64 + nt * 16 + l16;
#pragma unroll
        for (int mt = 0; mt < 2; ++mt)
#pragma unroll
            for (int r = 0; r < 4; ++r) {
                int row = wr * 32 + mt * 16 + quad * 4 + r;
                unsafeAtomicAdd(&c_all[(size_t)(m0 + row) * 128 + col], acc[mt][nt][r]);
            }
    }
}

// =====================================================================
// KS1: support q/k/v as batched MFMA. grid (16, 3): 64 support tokens x
// one of {Wq,Wk,Wv}. LN1 -> bf16 tile -> MFMA -> qkvs[w][1024][128].
// =====================================================================
#define K2_ST 136

__global__ __launch_bounds__(256) void ks1_qkv(
    const float* __restrict__ c_all, const bf16_t* __restrict__ wbf,
    const float* __restrict__ bq, const float* __restrict__ bk,
    const float* __restrict__ bv,
    const float* __restrict__ g1, const float* __restrict__ b1,
    float* __restrict__ qkvs)
{
    __shared__ bf16_t tT[64 * K2_ST];
    __shared__ bf16_t tW[128 * 128];

    const int tid  = threadIdx.x;
    const int wid  = tid >> 6;
    const int lane = tid & 63;
    const int quad = lane >> 4;
    const int l16  = lane & 15;
    const int bm   = blockIdx.x;        // 0..15
    const int w    = blockIdx.y;        // 0..2
    const int r0   = wid * 16;
    const int jr4  = lane >> 4;
    const int jp   = lane & 15;

    // DMA W_w
#pragma unroll
    for (int ii = 0; ii < 8; ++ii) {
        int i = 8 * wid + ii;
        int row = 4 * i + jr4;
        int c = jp ^ (row & 15);
        dma16(wbf + w * 16384 + row * 128 + c * 8, (char*)tW + i * 1024);
    }

    const float* Bw = (w == 0) ? bq : (w == 1) ? bk : bv;
    float bwr[8];
#pragma unroll
    for (int nt = 0; nt < 8; ++nt) bwr[nt] = Bw[nt * 16 + l16];

    // LN1 on 64 support rows (8 rows/wave in parallel, 2 passes)
    {
        const int g8 = lane >> 3, s8 = lane & 7;
        float g1a[16], b1a[16];
#pragma unroll
        for (int mm = 0; mm < 4; ++mm) {
            *(float4*)&g1a[mm * 4] = ((const float4*)(g1 + s8 * 16))[mm];
            *(float4*)&b1a[mm * 4] = ((const float4*)(b1 + s8 * 16))[mm];
        }
#pragma unroll
        for (int p = 0; p < 2; ++p) {
            int rloc = r0 + p * 8 + g8;
            const float* src = c_all + (size_t)(16384 + bm * 64 + rloc) * 128 + s8 * 16;
            float v[16];
#pragma unroll
            for (int mm = 0; mm < 4; ++mm) *(float4*)&v[mm * 4] = ((const float4*)src)[mm];
            float s = 0.f, q = 0.f;
#pragma unroll
            for (int m = 0; m < 16; ++m) { s += v[m]; q += v[m] * v[m]; }
#pragma unroll
            for (int m = 1; m < 8; m <<= 1) { s += __shfl_xor(s, m); q += __shfl_xor(q, m); }
            float mean = s * (1.f / 128.f);
            float var  = q * (1.f / 128.f) - mean * mean;
            float rs   = rsqrtf(var + LN_EPS);
            bf16x8 o0, o1;
#pragma unroll
            for (int m = 0; m < 8; ++m) o0[m] = (bf16_t)((v[m] - mean) * rs * g1a[m] + b1a[m]);
#pragma unroll
            for (int m = 0; m < 8; ++m) o1[m] = (bf16_t)((v[8 + m] - mean) * rs * g1a[8 + m] + b1a[8 + m]);
            *(bf16x8*)&tT[rloc * K2_ST + s8 * 16]     = o0;
            *(bf16x8*)&tT[rloc * K2_ST + s8 * 16 + 8] = o1;
        }
    }
    __syncthreads();   // DMA drained + tT visible

    floatx4 acc[8];
#pragma unroll
    for (int nt = 0; nt < 8; ++nt) acc[nt] = (floatx4)0.f;
#pragma unroll
    for (int ks = 0; ks < 4; ++ks) {
        bf16x8 a = *(const bf16x8*)&tT[(r0 + l16) * K2_ST + ks * 32 + quad * 8];
#pragma unroll
        for (int nt = 0; nt < 8; ++nt) {
            bf16x8 b = *(const bf16x8*)&tW[(nt * 16 + l16) * 128 + (((ks * 4 + quad) ^ l16) << 3)];
            acc[nt] = __builtin_amdgcn_mfma_f32_16x16x32_bf16(a, b, acc[nt], 0, 0, 0);
        }
    }
#pragma unroll
    for (int nt = 0; nt < 8; ++nt) {
        int col = nt * 16 + l16;
#pragma unroll
        for (int r = 0; r < 4; ++r) {
            int row = bm * 64 + r0 + quad * 4 + r;
            qkvs[(size_t)w * 131072 + (size_t)row * 128 + col] = acc[nt][r] + bwr[nt];
        }
    }
}

// =====================================================================
// KS2: per-task support attention tail: att -> softmax -> ctx -> LN2 ->
// @Wo^T+bo -> normalize -> pn. Wo DMA'd at start (single drain).
// =====================================================================
__global__ __launch_bounds__(256) void ks2_attn(
    const float* __restrict__ qkvs, const bf16_t* __restrict__ wbf,
    const float* __restrict__ bo,
    const float* __restrict__ g2, const float* __restrict__ b2,
    float* __restrict__ pn)
{
    __shared__ bf16_t tW[128 * 128];
    __shared__ float  q_[4][128], k_[4][128], v_[4][128];
    __shared__ float  att[4][4];
    __shared__ float  cs[4][128], cx[4][128];

    const int tid  = threadIdx.x;
    const int wid  = tid >> 6;
    const int lane = tid & 63;
    const int task = blockIdx.x;
    const int jr4  = lane >> 4;
    const int jp   = lane & 15;

#pragma unroll
    for (int ii = 0; ii < 8; ++ii) {   // DMA Wo
        int i = 8 * wid + ii;
        int row = 4 * i + jr4;
        int c = jp ^ (row & 15);
        dma16(wbf + 3 * 16384 + row * 128 + c * 8, (char*)tW + i * 1024);
    }
#pragma unroll
    for (int j = 0; j < 2; ++j) {      // load q,k,v (coalesced rows)
        int o = tid + j * 256, s = o >> 7, n = o & 127;
        size_t base = (size_t)(task * 4 + s) * 128 + n;
        q_[s][n] = qkvs[base];
        k_[s][n] = qkvs[131072 + base];
        v_[s][n] = qkvs[262144 + base];
    }
    __syncthreads();   // DMA drained, q/k/v visible

    if (tid < 16) {
        int i = tid >> 2, j = tid & 3;
        const float4* qv = (const float4*)q_[i];
        const float4* kv = (const float4*)k_[j];
        float a = 0.f;
#pragma unroll
        for (int k = 0; k < 32; ++k) {
            float4 x = qv[k], y = kv[k];
            a += x.x * y.x + x.y * y.y + x.z * y.z + x.w * y.w;
        }
        att[i][j] = a * (float)(1.0 / (11.313708498984761 + 1e-8));
    }
    __syncthreads();
    if (tid < 4) {  // exact softmax -> +1e-10 -> renorm -> clip
        float s0 = att[tid][0], s1 = att[tid][1], s2 = att[tid][2], s3 = att[tid][3];
        float m = fmaxf(fmaxf(s0, s1), fmaxf(s2, s3));
        float e0 = expf(s0 - m), e1 = expf(s1 - m), e2 = expf(s2 - m), e3 = expf(s3 - m);
        float se = e0 + e1 + e2 + e3;
        float a0 = e0 / se + 1e-10f, a1 = e1 / se + 1e-10f;
        float a2 = e2 / se + 1e-10f, a3 = e3 / se + 1e-10f;
        float t = a0 + a1 + a2 + a3;
        att[tid][0] = fminf(fmaxf(a0 / t, 1e-7f), 1.f);
        att[tid][1] = fminf(fmaxf(a1 / t, 1e-7f), 1.f);
        att[tid][2] = fminf(fmaxf(a2 / t, 1e-7f), 1.f);
        att[tid][3] = fminf(fmaxf(a3 / t, 1e-7f), 1.f);
    }
    __syncthreads();
#pragma unroll
    for (int j = 0; j < 2; ++j) {      // ctx = a @ v
        int o = tid + j * 256, s = o >> 7, n = o & 127;
        cx[s][n] = att[s][0] * v_[0][n] + att[s][1] * v_[1][n]
                 + att[s][2] * v_[2][n] + att[s][3] * v_[3][n];
    }
    __syncthreads();
    {   // LN2 -> cs
        float x0 = cx[wid][lane], x1 = cx[wid][64 + lane];
        float s = x0 + x1, q = x0 * x0 + x1 * x1;
#pragma unroll
        for (int m = 1; m < 64; m <<= 1) { s += __shfl_xor(s, m); q += __shfl_xor(q, m); }
        float mean = s * (1.f / 128.f);
        float var  = q * (1.f / 128.f) - mean * mean;
        float rs   = rsqrtf(var + LN_EPS);
        cs[wid][lane]      = (x0 - mean) * rs * g2[lane] + b2[lane];
        cs[wid][64 + lane] = (x1 - mean) * rs * g2[64 + lane] + b2[64 + lane];
    }
    __syncthreads();
#pragma unroll
    for (int j = 0; j < 2; ++j) {      // pf = LN2 @ Wo^T + bo -> cx
        int o = tid + j * 256, s = o >> 7, n = o & 127;
        const float4* c4 = (const float4*)cs[s];
        float a = 0.f;
#pragma unroll
        for (int c = 0; c < 16; ++c) {
            bf16x8 wv = *(const bf16x8*)&tW[n * 128 + ((c ^ (n & 15)) << 3)];
            float4 a0 = c4[c * 2], a1 = c4[c * 2 + 1];
            a += a0.x * (float)wv[0] + a0.y * (float)wv[1]
               + a0.z * (float)wv[2] + a0.w * (float)wv[3]
               + a1.x * (float)wv[4] + a1.y * (float)wv[5]
               + a1.z * (float)wv[6] + a1.w * (float)wv[7];
        }
        cx[s][n] = a + bo[n];
    }
    __syncthreads();
    {   // normalize -> pn
        float x0 = cx[wid][lane], x1 = cx[wid][64 + lane];
        float q = x0 * x0 + x1 * x1;
#pragma unroll
        for (int m = 1; m < 64; m <<= 1) q += __shfl_xor(q, m);
        float inv = 1.f / fmaxf(sqrtf(q), 1e-8f);
        float* dst = pn + (size_t)(task * 4 + wid) * 128;
        dst[lane]      = x0 * inv;
        dst[64 + lane] = x1 * inv;
    }
}

// =====================================================================
// KQ: query tail + logits. 1 block = 1 task. LN1 -> MFMA(Wv) -> LN2 ->
// MFMA(Wo) -> normalize -> logits. 3 barriers, 2 global drains.
// =====================================================================
__global__ __launch_bounds__(256) void kq_query(
    const float* __restrict__ c_all, const bf16_t* __restrict__ wbf,
    const float* __restrict__ bv, const float* __restrict__ bo,
    const float* __restrict__ g1, const float* __restrict__ b1,
    const float* __restrict__ g2, const float* __restrict__ b2,
    const float* __restrict__ pn, float* __restrict__ out)
{
    __shared__ bf16_t tT[64 * K2_ST];
    __shared__ bf16_t tW[128 * 128];
    __shared__ float  pl[4][132];

    const int tid  = threadIdx.x;
    const int wid  = tid >> 6;
    const int lane = tid & 63;
    const int quad = lane >> 4;
    const int l16  = lane & 15;
    const int task = blockIdx.x;
    const int t0   = task * 64;
    const int r0   = wid * 16;
    const int jr4  = lane >> 4;
    const int jp   = lane & 15;

#pragma unroll
    for (int ii = 0; ii < 8; ++ii) {   // DMA Wv
        int i = 8 * wid + ii;
        int row = 4 * i + jr4;
        int c = jp ^ (row & 15);
        dma16(wbf + 2 * 16384 + row * 128 + c * 8, (char*)tW + i * 1024);
    }
    if (tid < 128) {                   // prototypes
        int r = tid >> 5, c4 = tid & 31;
        *(float4*)&pl[r][c4 * 4] = *(const float4*)(pn + ((size_t)task * 4 + r) * 128 + c4 * 4);
    }

    float bvr[8], g2r[8], b2r[8], bor[8];
#pragma unroll
    for (int nt = 0; nt < 8; ++nt) {
        int col = nt * 16 + l16;
        bvr[nt] = bv[col]; g2r[nt] = g2[col]; b2r[nt] = b2[col]; bor[nt] = bo[col];
    }

    // LN1 -> tT
    {
        const int g8 = lane >> 3, s8 = lane & 7;
        float g1a[16], b1a[16];
#pragma unroll
        for (int mm = 0; mm < 4; ++mm) {
            *(float4*)&g1a[mm * 4] = ((const float4*)(g1 + s8 * 16))[mm];
            *(float4*)&b1a[mm * 4] = ((const float4*)(b1 + s8 * 16))[mm];
        }
#pragma unroll
        for (int p = 0; p < 2; ++p) {
            int rloc = r0 + p * 8 + g8;
            const float* src = c_all + (size_t)(t0 + rloc) * 128 + s8 * 16;
            float v[16];
#pragma unroll
            for (int mm = 0; mm < 4; ++mm) *(float4*)&v[mm * 4] = ((const float4*)src)[mm];
            float s = 0.f, q = 0.f;
#pragma unroll
            for (int m = 0; m < 16; ++m) { s += v[m]; q += v[m] * v[m]; }
#pragma unroll
            for (int m = 1; m < 8; m <<= 1) { s += __shfl_xor(s, m); q += __shfl_xor(q, m); }
            float mean = s * (1.f / 128.f);
            float var  = q * (1.f / 128.f) - mean * mean;
            float rs   = rsqrtf(var + LN_EPS);
            bf16x8 o0, o1;
#pragma unroll
            for (int m = 0; m < 8; ++m) o0[m] = (bf16_t)((v[m] - mean) * rs * g1a[m] + b1a[m]);
#pragma unroll
            for (int m = 0; m < 8; ++m) o1[m] = (bf16_t)((v[8 + m] - mean) * rs * g1a[8 + m] + b1a[8 + m]);
            *(bf16x8*)&tT[rloc * K2_ST + s8 * 16]     = o0;
            *(bf16x8*)&tT[rloc * K2_ST + s8 * 16 + 8] = o1;
        }
    }
    __syncthreads();   // B1: Wv+pl drained, tT visible

    // MFMA1: v = LN1 @ Wv^T + bv
    floatx4 acc[8];
#pragma unroll
    for (int nt = 0; nt < 8; ++nt) acc[nt] = (floatx4)0.f;
#pragma unroll
    for (int ks = 0; ks < 4; ++ks) {
        bf16x8 a = *(const bf16x8*)&tT[(r0 + l16) * K2_ST + ks * 32 + quad * 8];
#pragma unroll
        for (int nt = 0; nt < 8; ++nt) {
            bf16x8 b = *(const bf16x8*)&tW[(nt * 16 + l16) * 128 + (((ks * 4 + quad) ^ l16) << 3)];
            acc[nt] = __builtin_amdgcn_mfma_f32_16x16x32_bf16(a, b, acc[nt], 0, 0, 0);
        }
    }
#pragma unroll
    for (int nt = 0; nt < 8; ++nt)
#pragma unroll
        for (int r = 0; r < 4; ++r) acc[nt][r] += bvr[nt];

    // LN2 in-register -> tT (wave-private rows)
#pragma unroll
    for (int r = 0; r < 4; ++r) {
        float s = 0.f, q = 0.f;
#pragma unroll
        for (int nt = 0; nt < 8; ++nt) { float x = acc[nt][r]; s += x; q += x * x; }
#pragma unroll
        for (int m = 1; m < 16; m <<= 1) { s += __shfl_xor(s, m); q += __shfl_xor(q, m); }
        float mean = s * (1.f / 128.f);
        float var  = q * (1.f / 128.f) - mean * mean;
        float rs   = rsqrtf(var + LN_EPS);
        int row = r0 + quad * 4 + r;
#pragma unroll
        for (int nt = 0; nt < 8; ++nt)
            tT[row * K2_ST + nt * 16 + l16] = (bf16_t)((acc[nt][r] - mean) * rs * g2r[nt] + b2r[nt]);
    }
    __syncthreads();   // B2: all waves done reading Wv
#pragma unroll
    for (int ii = 0; ii < 8; ++ii) {   // DMA Wo
        int i = 8 * wid + ii;
        int row = 4 * i + jr4;
        int c = jp ^ (row & 15);
        dma16(wbf + 3 * 16384 + row * 128 + c * 8, (char*)tW + i * 1024);
    }
    __syncthreads();   // B3: Wo drained

    // MFMA2: qf = LN2 @ Wo^T
    floatx4 acc2[8];
#pragma unroll
    for (int nt = 0; nt < 8; ++nt) acc2[nt] = (floatx4)0.f;
#pragma unroll
    for (int ks = 0; ks < 4; ++ks) {
        bf16x8 a = *(const bf16x8*)&tT[(r0 + l16) * K2_ST + ks * 32 + quad * 8];
#pragma unroll
        for (int nt = 0; nt < 8; ++nt) {
            bf16x8 b = *(const bf16x8*)&tW[(nt * 16 + l16) * 128 + (((ks * 4 + quad) ^ l16) << 3)];
            acc2[nt] = __builtin_amdgcn_mfma_f32_16x16x32_bf16(a, b, acc2[nt], 0, 0, 0);
        }
    }

    // normalize + logits
#pragma unroll
    for (int r = 0; r < 4; ++r) {
        float st[8]; float q = 0.f;
#pragma unroll
        for (int nt = 0; nt < 8; ++nt) {
            float x = acc2[nt][r] + bor[nt]; st[nt] = x; q += x * x;
        }
#pragma unroll
        for (int m = 1; m < 16; m <<= 1) q += __shfl_xor(q, m);
        float inv = 1.f / fmaxf(sqrtf(q), 1e-8f);
        float d0 = 0.f, d1 = 0.f, d2 = 0.f, d3 = 0.f;
#pragma unroll
        for (int nt = 0; nt < 8; ++nt) {
            float xn = st[nt] * inv;
            int col = nt * 16 + l16;
            d0 += xn * pl[0][col]; d1 += xn * pl[1][col];
            d2 += xn * pl[2][col]; d3 += xn * pl[3][col];
        }
#pragma unroll
        for (int m = 1; m < 16; m <<= 1) {
            d0 += __shfl_xor(d0, m); d1 += __shfl_xor(d1, m);
            d2 += __shfl_xor(d2, m); d3 += __shfl_xor(d3, m);
        }
        if (l16 == 0) {
            int qi = r0 + quad * 4 + r;
            float* o = out + (size_t)task * 256 + qi * 4;
            o[0] = d0 * 10.f; o[1] = d1 * 10.f; o[2] = d2 * 10.f; o[3] = d3 * 10.f;
        }
    }
}

// =====================================================================
extern "C" void kernel_launch(void* const* d_in, const int* in_sizes, int n_in,
                              void* d_out, int out_size, void* d_ws, size_t ws_size,
                              hipStream_t stream)
{
    const float* simg = (const float*)d_in[0];
    const float* stxt = (const float*)d_in[1];
    const float* qimg = (const float*)d_in[3];
    const float* qtxt = (const float*)d_in[4];
    const float* Wi = (const float*)d_in[5];
    const float* bi = (const float*)d_in[6];
    const float* Wt = (const float*)d_in[7];
    const float* bt = (const float*)d_in[8];
    const float* g1 = (const float*)d_in[9];
    const float* b1 = (const float*)d_in[10];
    const float* Wq = (const float*)d_in[11];
    const float* bq = (const float*)d_in[12];
    const float* Wk = (const float*)d_in[13];
    const float* bk = (const float*)d_in[14];
    const float* Wv = (const float*)d_in[15];
    const float* bv = (const float*)d_in[16];
    const float* g2 = (const float*)d_in[17];
    const float* b2 = (const float*)d_in[18];
    const float* Wo = (const float*)d_in[19];
    const float* bo = (const float*)d_in[20];
    float* out = (float*)d_out;

    float*  c_all = (float*)d_ws;                            // 17408 x 128 f32
    bf16_t* wbf   = (bf16_t*)(c_all + (size_t)17408 * 128);  // 425984 bf16
    float*  qkvs  = (float*)(wbf + 425984);                  // 3 x 1024 x 128 f32
    float*  pn    = qkvs + (size_t)3 * 131072;               // 1024 x 128 f32

    k0_prep<<<2592, 256, 0, stream>>>(bi, bt, Wq, Wk, Wv, Wo, Wi, Wt, c_all, wbf);
    k1_gemm<<<dim3(272, 4), 256, 0, stream>>>(qimg, qtxt, simg, stxt, wbf, c_all);
    ks1_qkv<<<dim3(16, 3), 256, 0, stream>>>(c_all, wbf, bq, bk, bv, g1, b1, qkvs);
    ks2_attn<<<256, 256, 0, stream>>>(qkvs, wbf, bo, g2, b2, pn);
    kq_query<<<256, 256, 0, stream>>>(c_all, wbf, bv, bo, g1, b1, g2, b2, pn, out);
}